// Round 6
// baseline (60.601 us; speedup 1.0000x reference)
//
#include <hip/hip_runtime.h>
#include <math.h>

#define NW 599
#define NRR 598

__device__ inline float wave_sum(float v) {
#pragma unroll
  for (int o = 32; o > 0; o >>= 1) v += __shfl_down(v, o);
  return v;
}

// all 256 threads participate; result broadcast to all
__device__ inline float block_sum(float v, float* scr, int tid) {
  v = wave_sum(v);
  if ((tid & 63) == 0) scr[tid >> 6] = v;
  __syncthreads();
  float r = scr[0] + scr[1] + scr[2] + scr[3];
  __syncthreads();
  return r;
}

// One block per row. 3 chunks of the 9000-float row are streamed through a
// single 12 KB LDS buffer with register-staged prefetch (issue loads for
// chunk c+1 right after the barrier, before computing chunk c's windows ->
// HBM latency hides under the softargmax VALU work; barriers do NOT drain
// reg-destined vmcnt). Peaks land in LDS; features/MLP/LN run in-block.
__global__ __launch_bounds__(256, 6) void prv_fused(
    const float* __restrict__ x, const float* __restrict__ W1,
    const float* __restrict__ b1, const float* __restrict__ W2,
    const float* __restrict__ b2, const float* __restrict__ gamma,
    const float* __restrict__ beta, float* __restrict__ out) {
  __shared__ float s[3024];     // staging: chunk of 754 float4
  __shared__ float s_pk[600];   // peaks
  __shared__ float s_red[96];
  __shared__ float s_pow[12];
  __shared__ float s_feat[5];
  __shared__ float s_h1[64];
  __shared__ float s_scr[4];

  const int row = blockIdx.x;
  const int tid = threadIdx.x;
  const float4* __restrict__ src = (const float4*)(x + (size_t)row * 9000);

  // ---- prologue: issue chunk 0 loads (nf4 = 754) ----
  float4 r0, r1, r2;
  r0 = src[tid];
  r1 = src[tid + 256];
  if (tid + 512 < 754) r2 = src[tid + 512];

#pragma unroll
  for (int c = 0; c < 3; ++c) {
    const int nf4 = (c < 2) ? 754 : 750;
    float4* sb = (float4*)s;
    sb[tid] = r0;                        // waits vmcnt here only
    sb[tid + 256] = r1;
    if (tid + 512 < nf4) sb[tid + 512] = r2;
    __syncthreads();
    if (c < 2) {                         // prefetch chunk c+1 into regs
      const int nn = (c == 0) ? 754 : 750;
      const float4* p2 = src + 750 * (c + 1);
      r0 = p2[tid];
      r1 = p2[tid + 256];
      if (tid + 512 < nn) r2 = p2[tid + 512];
    }
    const int nw = min(NW - c * 200, 200);
    if (tid < nw) {                      // window w = 200c + tid
      const float* p = s + 15 * tid;     // stride 15 (odd) -> 2-way max, free
      float m = p[0];
#pragma unroll
      for (int j = 1; j < 30; ++j) m = fmaxf(m, p[j]);
      float se = 0.f, we = 0.f;
#pragma unroll
      for (int j = 0; j < 30; ++j) {
        float e = __expf((p[j] - m) * 10.0f);  // temp = 0.1
        se += e;
        we += (float)j * e;
      }
      const int w = c * 200 + tid;
      s_pk[w] = we / se + 15.0f * (float)w;
    }
    __syncthreads();
  }

  // ---- features from peaks (rr recomputed from s_pk on the fly) ----
  const float inv30 = 1.0f / 30.0f;

  float v = 0.f;
  for (int n = tid; n < NRR; n += 256)
    v += (s_pk[n + 1] - s_pk[n]) * inv30;
  const float mean_rr = block_sum(v, s_scr, tid) * (1.0f / (float)NRR);

  float sq = 0.f, d2 = 0.f;
  for (int n = tid; n < NRR; n += 256) {
    float rrn = (s_pk[n + 1] - s_pk[n]) * inv30;
    float r = rrn - mean_rr;
    sq += r * r;
    if (n < NRR - 1) {
      float rrn1 = (s_pk[n + 2] - s_pk[n + 1]) * inv30;
      float df = rrn1 - rrn;
      d2 += df * df;
    }
  }
  const float sdnn = sqrtf(block_sum(sq, s_scr, tid) * (1.0f / (float)(NRR - 1)));
  const float rmssd =
      sqrtf(block_sum(d2, s_scr, tid) * (1.0f / (float)(NRR - 1)) + 1e-6f);

  // ---- sparse DFT: rfft(rr, 1024) bins k=2..13 (LF 2..5, HF 6..13) ----
  float re[12], im[12];
#pragma unroll
  for (int k = 0; k < 12; ++k) { re[k] = 0.f; im[k] = 0.f; }
  for (int n = tid; n < NRR; n += 256) {
    float rv = (s_pk[n + 1] - s_pk[n]) * inv30;
#pragma unroll
    for (int kk = 0; kk < 12; ++kk) {
      int m = ((kk + 2) * n) & 1023;                   // exact integer phase
      float ang = (float)m * 6.13592315154256491e-3f;  // 2*pi/1024
      float sn, cs;
      __sincosf(ang, &sn, &cs);
      re[kk] = fmaf(rv, cs, re[kk]);
      im[kk] = fmaf(-rv, sn, im[kk]);
    }
  }
  const int wid = tid >> 6, lane = tid & 63;
#pragma unroll
  for (int kk = 0; kk < 12; ++kk) {
    float r = wave_sum(re[kk]);
    float i2 = wave_sum(im[kk]);
    if (lane == 0) {
      s_red[wid * 24 + kk] = r;
      s_red[wid * 24 + 12 + kk] = i2;
    }
  }
  __syncthreads();
  if (tid < 12) {
    float r = s_red[tid] + s_red[24 + tid] + s_red[48 + tid] + s_red[72 + tid];
    float i2 =
        s_red[12 + tid] + s_red[36 + tid] + s_red[60 + tid] + s_red[84 + tid];
    s_pow[tid] = r * r + i2 * i2;
  }
  __syncthreads();
  if (tid == 0) {
    float lf = s_pow[0] + s_pow[1] + s_pow[2] + s_pow[3];
    float hf = 0.f;
#pragma unroll
    for (int k = 4; k < 12; ++k) hf += s_pow[k];
    s_feat[0] = mean_rr;
    s_feat[1] = rmssd;
    s_feat[2] = sdnn;
    s_feat[3] = lf;
    s_feat[4] = hf;
  }
  __syncthreads();

  // ---- MLP layer 1: (5) @ (5,64) + b1, relu ----
  if (tid < 64) {
    float acc = b1[tid];
#pragma unroll
    for (int i = 0; i < 5; ++i) acc = fmaf(s_feat[i], W1[i * 64 + tid], acc);
    s_h1[tid] = fmaxf(acc, 0.f);
  }
  __syncthreads();

  // ---- MLP layer 2: (64) @ (64,128) + b2 ----
  float h2 = 0.f;
  if (tid < 128) {
    float acc = b2[tid];
#pragma unroll 8
    for (int i = 0; i < 64; ++i) acc = fmaf(s_h1[i], W2[i * 128 + tid], acc);
    h2 = acc;
  }

  // ---- LayerNorm over 128 (two-pass) ----
  float sv = (tid < 128) ? h2 : 0.f;
  const float mu = block_sum(sv, s_scr, tid) * (1.0f / 128.0f);
  float dv = (tid < 128) ? (h2 - mu) * (h2 - mu) : 0.f;
  const float var = block_sum(dv, s_scr, tid) * (1.0f / 128.0f);
  if (tid < 128) {
    out[(size_t)row * 128 + tid] =
        (h2 - mu) * rsqrtf(var + 1e-5f) * gamma[tid] + beta[tid];
  }
}

extern "C" void kernel_launch(void* const* d_in, const int* in_sizes, int n_in,
                              void* d_out, int out_size, void* d_ws,
                              size_t ws_size, hipStream_t stream) {
  const float* x = (const float*)d_in[0];
  const float* W1 = (const float*)d_in[1];
  const float* b1 = (const float*)d_in[2];
  const float* W2 = (const float*)d_in[3];
  const float* b2 = (const float*)d_in[4];
  const float* gamma = (const float*)d_in[5];
  const float* beta = (const float*)d_in[6];
  float* out = (float*)d_out;

  const int B = in_sizes[0] / 9000;
  prv_fused<<<B, 256, 0, stream>>>(x, W1, b1, W2, b2, gamma, beta, out);
}